// Round 1
// baseline (20213.553 us; speedup 1.0000x reference)
//
#include <hip/hip_runtime.h>
#include <math.h>

#define BATCH 64
#define DM 768
#define NHD 12
#define HDIM 64
#define NLAYER 8
#define NLOC 49
#define NSC 256
#define ATT_SCALE 0.125f
#define QT 32

// ------------------------------------------------------------------
// rope tables
// local: (B, 49, 32) cos/sin ; scene: (256, 32) cos/sin (batch-invariant)
// ang dims: d<16 -> x coord, periods[d]; 16<=d<32 -> y coord, periods[d-16]
// ------------------------------------------------------------------
__global__ void rope_local_k(const float* __restrict__ centers, const float* __restrict__ scales,
                             const float* __restrict__ periods, float* __restrict__ lcos,
                             float* __restrict__ lsin) {
  int t = blockIdx.x * blockDim.x + threadIdx.x;
  const int total = BATCH * NLOC * 32;
  if (t >= total) return;
  int d = t & 31;
  int r = (t >> 5) % NLOC;
  int b = t / (NLOC * 32);
  int pi = d & 15;
  float gx = ((r % 7) + 0.5f) / 7.0f - 0.5f;   // x = col
  float gy = ((r / 7) + 0.5f) / 7.0f - 0.5f;   // y = row
  float coord = (d < 16) ? (centers[b * 2 + 0] + scales[b * 2 + 0] * gx)
                         : (centers[b * 2 + 1] + scales[b * 2 + 1] * gy);
  float ang = 6.283185307179586f * coord / periods[pi];
  lcos[t] = cosf(ang);
  lsin[t] = sinf(ang);
}

__global__ void rope_scene_k(const float* __restrict__ periods, float* __restrict__ scos,
                             float* __restrict__ ssin) {
  int t = blockIdx.x * blockDim.x + threadIdx.x;
  const int total = NSC * 32;
  if (t >= total) return;
  int d = t & 31;
  int r = t >> 5;
  int pi = d & 15;
  float coord = (d < 16) ? ((r % 16) + 0.5f) / 16.0f : ((r / 16) + 0.5f) / 16.0f;
  float ang = 6.283185307179586f * coord / periods[pi];
  scos[t] = cosf(ang);
  ssin[t] = sinf(ang);
}

// ------------------------------------------------------------------
// init: local -> out[0:B*49*D], broadcast scene_tokens -> out[...:B*256*D]
// ------------------------------------------------------------------
__global__ void init_out_k(const float* __restrict__ local_in, const float* __restrict__ scene_tok,
                           float* __restrict__ out) {
  int t = blockIdx.x * blockDim.x + threadIdx.x;
  const int NL = BATCH * NLOC * DM;
  const int NS = BATCH * NSC * DM;
  if (t < NL) out[t] = local_in[t];
  else if (t < NL + NS) out[t] = scene_tok[(t - NL) % (NSC * DM)];
}

// ------------------------------------------------------------------
// GEMM: C[M,N] = A[M,K] @ W[K,N] + bias
// MODE 0: plain   MODE 1: exact GELU   MODE 2: res + gate*(acc+bias)
// M % 64 == 0, N % 128 == 0, K % 16 == 0 (always true here)
// tile 64x128, 256 threads, 4x8 per thread
// ------------------------------------------------------------------
template <int MODE>
__global__ __launch_bounds__(256) void gemm_k(const float* __restrict__ A,
                                              const float* __restrict__ W,
                                              const float* __restrict__ bias, float* C,
                                              const float* res, const float* gate, int M, int N,
                                              int K) {
  __shared__ float As[16][64];
  __shared__ float Ws[16][128];
  const int tid = threadIdx.x;
  const int tx = tid & 15, ty = tid >> 4;
  const int bm = blockIdx.y << 6;
  const int bn = blockIdx.x << 7;
  const int lm = tid >> 2;
  const int lk4 = (tid & 3) << 2;
  const int wk = tid >> 4;
  const int wn4 = (tid & 15) << 2;
  const float* Ap = A + (size_t)(bm + lm) * K + lk4;
  const float* Wp0 = W + (size_t)wk * N + bn + wn4;
  float acc[4][8];
#pragma unroll
  for (int i = 0; i < 4; ++i)
#pragma unroll
    for (int j = 0; j < 8; ++j) acc[i][j] = 0.f;

  for (int k0 = 0; k0 < K; k0 += 16) {
    float4 av = *(const float4*)(Ap + k0);
    float4 wv0 = *(const float4*)(Wp0 + (size_t)k0 * N);
    float4 wv1 = *(const float4*)(Wp0 + (size_t)k0 * N + 64);
    __syncthreads();
    As[lk4 + 0][lm] = av.x;
    As[lk4 + 1][lm] = av.y;
    As[lk4 + 2][lm] = av.z;
    As[lk4 + 3][lm] = av.w;
    *(float4*)&Ws[wk][wn4] = wv0;
    *(float4*)&Ws[wk][wn4 + 64] = wv1;
    __syncthreads();
#pragma unroll
    for (int kk = 0; kk < 16; ++kk) {
      float4 a4 = *(const float4*)&As[kk][ty << 2];
      float4 b0 = *(const float4*)&Ws[kk][tx << 2];
      float4 b1 = *(const float4*)&Ws[kk][64 + (tx << 2)];
      float aa[4] = {a4.x, a4.y, a4.z, a4.w};
      float bb[8] = {b0.x, b0.y, b0.z, b0.w, b1.x, b1.y, b1.z, b1.w};
#pragma unroll
      for (int i = 0; i < 4; ++i)
#pragma unroll
        for (int j = 0; j < 8; ++j) acc[i][j] = fmaf(aa[i], bb[j], acc[i][j]);
    }
  }
  const int row0 = bm + (ty << 2);
#pragma unroll
  for (int i = 0; i < 4; ++i) {
    const size_t rb = (size_t)(row0 + i) * N;
#pragma unroll
    for (int g = 0; g < 2; ++g) {
      const int col = bn + (g << 6) + (tx << 2);
#pragma unroll
      for (int j = 0; j < 4; ++j) {
        float v = acc[i][(g << 2) + j] + bias[col + j];
        if (MODE == 1) v = 0.5f * v * (1.0f + erff(v * 0.7071067811865475f));
        if (MODE == 2) {
          float gg = gate ? gate[col + j] : 1.0f;
          v = res[rb + col + j] + gg * v;
        }
        C[rb + col + j] = v;
      }
    }
  }
}

// ------------------------------------------------------------------
// LayerNorm over D=768; one wave per row; 4 rows per block
// ------------------------------------------------------------------
__global__ __launch_bounds__(256) void ln_k(const float* __restrict__ X,
                                            const float* __restrict__ w,
                                            const float* __restrict__ bb, float* __restrict__ Y,
                                            int rows) {
  const int wid = threadIdx.x >> 6, lane = threadIdx.x & 63;
  const int row = blockIdx.x * 4 + wid;
  if (row >= rows) return;
  const float* x = X + (size_t)row * DM;
  float v[12];
  float s = 0.f;
#pragma unroll
  for (int j = 0; j < 12; ++j) {
    v[j] = x[lane + 64 * j];
    s += v[j];
  }
#pragma unroll
  for (int o = 32; o; o >>= 1) s += __shfl_xor(s, o, 64);
  float mean = s * (1.0f / 768.0f);
  float q = 0.f;
#pragma unroll
  for (int j = 0; j < 12; ++j) {
    float d0 = v[j] - mean;
    q += d0 * d0;
  }
#pragma unroll
  for (int o = 32; o; o >>= 1) q += __shfl_xor(q, o, 64);
  float inv = rsqrtf(q * (1.0f / 768.0f) + 1e-6f);
#pragma unroll
  for (int j = 0; j < 12; ++j) {
    int d0 = lane + 64 * j;
    Y[(size_t)row * DM + d0] = (v[j] - mean) * inv * w[d0] + bb[d0];
  }
}

// ------------------------------------------------------------------
// Fused attention for one (b, h, q-tile of 32):
//  - rope Q tile into LDS, rope K chunk-wise into LDS (transposed, padded)
//  - scores (<=32x256) in LDS, stable softmax, AV with V from global
// Q/K/V row strides parameterized so backend qkv (stride 2304) reuses this.
// rope idx = b*bstride + n*32 (+d&31); bstride=0 => batch-shared (scene)
// ------------------------------------------------------------------
__global__ __launch_bounds__(256) void attn_k(const float* __restrict__ Q, int qs,
                                              const float* __restrict__ K, int ks,
                                              const float* __restrict__ V, int vs,
                                              float* __restrict__ O,
                                              const float* __restrict__ qcos,
                                              const float* __restrict__ qsin, int qbs,
                                              const float* __restrict__ kcos,
                                              const float* __restrict__ ksin, int kbs, int Nq,
                                              int Nk) {
  __shared__ float q_s[QT][64];
  __shared__ float k_sT[64][68];  // [d][m] padded: float4 along m, 2-way banks (free)
  __shared__ float sc[QT][NSC];
  const int tid = threadIdx.x;
  const int nQT = (Nq + QT - 1) / QT;
  const int qt = blockIdx.x % nQT;
  const int h = (blockIdx.x / nQT) % NHD;
  const int b = blockIdx.x / (nQT * NHD);
  const int n0 = qt * QT;
  const int nrows = (Nq - n0 < QT) ? (Nq - n0) : QT;

  // roped Q tile
  for (int idx = tid; idx < nrows * 64; idx += 256) {
    int r = idx >> 6, d = idx & 63, dd = d & 31;
    int n = n0 + r;
    size_t base = ((size_t)b * Nq + n) * qs + h * 64;
    float c = qcos[(size_t)b * qbs + n * 32 + dd];
    float s = qsin[(size_t)b * qbs + n * 32 + dd];
    float x1 = Q[base + dd], x2 = Q[base + dd + 32];
    q_s[r][d] = (d < 32) ? (x1 * c - x2 * s) : (x1 * s + x2 * c);
  }

  const int rt = tid >> 4, mt = tid & 15;
  const int r0 = rt * 2;
  for (int m0 = 0; m0 < Nk; m0 += 64) {
    int mc = (Nk - m0 < 64) ? (Nk - m0) : 64;
    __syncthreads();  // q_s ready (1st iter); k_sT reuse safe (later iters)
    for (int idx = tid; idx < mc * 64; idx += 256) {
      int r = idx >> 6, d = idx & 63, dd = d & 31;
      int m = m0 + r;
      size_t base = ((size_t)b * Nk + m) * ks + h * 64;
      float c = kcos[(size_t)b * kbs + m * 32 + dd];
      float s = ksin[(size_t)b * kbs + m * 32 + dd];
      float x1 = K[base + dd], x2 = K[base + dd + 32];
      k_sT[d][r] = (d < 32) ? (x1 * c - x2 * s) : (x1 * s + x2 * c);
    }
    __syncthreads();
    float a0[4] = {0, 0, 0, 0}, a1[4] = {0, 0, 0, 0};
#pragma unroll 8
    for (int d = 0; d < 64; ++d) {
      float4 kv = *(const float4*)&k_sT[d][mt << 2];
      float q0 = q_s[r0][d];
      float q1 = q_s[r0 + 1][d];
      a0[0] = fmaf(q0, kv.x, a0[0]);
      a0[1] = fmaf(q0, kv.y, a0[1]);
      a0[2] = fmaf(q0, kv.z, a0[2]);
      a0[3] = fmaf(q0, kv.w, a0[3]);
      a1[0] = fmaf(q1, kv.x, a1[0]);
      a1[1] = fmaf(q1, kv.y, a1[1]);
      a1[2] = fmaf(q1, kv.z, a1[2]);
      a1[3] = fmaf(q1, kv.w, a1[3]);
    }
    const int mloc = mt << 2;
    if (r0 < nrows) {
#pragma unroll
      for (int j = 0; j < 4; ++j)
        if (mloc + j < mc) sc[r0][m0 + mloc + j] = a0[j] * ATT_SCALE;
    }
    if (r0 + 1 < nrows) {
#pragma unroll
      for (int j = 0; j < 4; ++j)
        if (mloc + j < mc) sc[r0 + 1][m0 + mloc + j] = a1[j] * ATT_SCALE;
    }
  }
  __syncthreads();

  // softmax per row (wave-per-row, strided)
  const int wid = tid >> 6, lane = tid & 63;
  for (int r = wid; r < nrows; r += 4) {
    float mx = -1e30f;
    for (int m = lane; m < Nk; m += 64) mx = fmaxf(mx, sc[r][m]);
#pragma unroll
    for (int o = 32; o; o >>= 1) mx = fmaxf(mx, __shfl_xor(mx, o, 64));
    float sum = 0.f;
    for (int m = lane; m < Nk; m += 64) {
      float e = __expf(sc[r][m] - mx);
      sc[r][m] = e;
      sum += e;
    }
#pragma unroll
    for (int o = 32; o; o >>= 1) sum += __shfl_xor(sum, o, 64);
    float inv = 1.0f / sum;
    for (int m = lane; m < Nk; m += 64) sc[r][m] *= inv;
  }
  __syncthreads();

  // AV: lane=dim, 8 rows per wave reuse each V load
  float acc[8] = {0, 0, 0, 0, 0, 0, 0, 0};
  for (int m = 0; m < Nk; ++m) {
    float v = V[((size_t)b * Nk + m) * vs + h * 64 + lane];
#pragma unroll
    for (int rr = 0; rr < 8; ++rr) acc[rr] = fmaf(sc[wid + (rr << 2)][m], v, acc[rr]);
  }
#pragma unroll
  for (int rr = 0; rr < 8; ++rr) {
    int r = wid + (rr << 2);
    if (r < nrows) O[((size_t)b * Nq + n0 + r) * DM + h * 64 + lane] = acc[rr];
  }
}

// ------------------------------------------------------------------
extern "C" void kernel_launch(void* const* d_in, const int* in_sizes, int n_in, void* d_out,
                              int out_size, void* d_ws, size_t ws_size, hipStream_t stream) {
  const float* local_in = (const float*)d_in[0];
  const float* centers = (const float*)d_in[1];
  const float* scales = (const float*)d_in[2];
  const float* scene_tok = (const float*)d_in[3];
  const float* periods = (const float*)d_in[4];
  const float* read_gate = (const float*)d_in[5];
  const float* write_gate = (const float*)d_in[6];
  const float* ln1w = (const float*)d_in[7];
  const float* ln1b = (const float*)d_in[8];
  const float* ln2w = (const float*)d_in[9];
  const float* ln2b = (const float*)d_in[10];
  const float* Wqkv = (const float*)d_in[11];
  const float* bqkv = (const float*)d_in[12];
  const float* Wp = (const float*)d_in[13];
  const float* bp = (const float*)d_in[14];
  const float* W1 = (const float*)d_in[15];
  const float* b1 = (const float*)d_in[16];
  const float* W2 = (const float*)d_in[17];
  const float* b2 = (const float*)d_in[18];
  const float* rqW = (const float*)d_in[19];
  const float* rqb = (const float*)d_in[20];
  const float* rkW = (const float*)d_in[21];
  const float* rkb = (const float*)d_in[22];
  const float* rvW = (const float*)d_in[23];
  const float* rvb = (const float*)d_in[24];
  const float* roW = (const float*)d_in[25];
  const float* rob = (const float*)d_in[26];
  const float* wqW = (const float*)d_in[27];
  const float* wqb = (const float*)d_in[28];
  const float* wkW = (const float*)d_in[29];
  const float* wkb = (const float*)d_in[30];
  const float* wvW = (const float*)d_in[31];
  const float* wvb = (const float*)d_in[32];
  const float* woW = (const float*)d_in[33];
  const float* wob = (const float*)d_in[34];

  float* out = (float*)d_out;
  float* local = out;                               // (B*49, 768)
  float* scene = out + (size_t)BATCH * NLOC * DM;   // (B*256, 768)

  float* ws = (float*)d_ws;
  const size_t SZB = (size_t)BATCH * NSC * DM;  // 12.58M floats
  float* bufQ = ws;
  float* bufK = ws + SZB;
  float* bufV = ws + 2 * SZB;
  float* bufO = ws + 3 * SZB;
  float* bufH = bufK;  // LN output: bufK is dead while bufH live (see schedule)
  float* lcos = ws + 4 * SZB;
  float* lsin = lcos + BATCH * NLOC * 32;
  float* scos = lsin + BATCH * NLOC * 32;
  float* ssin = scos + NSC * 32;

  const int ML = BATCH * NLOC;  // 3136
  const int MS = BATCH * NSC;   // 16384
  const int totOut = (ML + MS) * DM;

  init_out_k<<<(totOut + 255) / 256, 256, 0, stream>>>(local_in, scene_tok, out);
  rope_local_k<<<(BATCH * NLOC * 32 + 255) / 256, 256, 0, stream>>>(centers, scales, periods,
                                                                    lcos, lsin);
  rope_scene_k<<<(NSC * 32 + 255) / 256, 256, 0, stream>>>(periods, scos, ssin);

  const size_t DD = (size_t)DM * DM;
  const int LBS = NLOC * 32;  // local rope batch stride
  for (int i = 0; i < NLAYER; ++i) {
    // ---- read cross-attn: local(49q) <- scene(256kv), gated residual into local
    gemm_k<0><<<dim3(6, 49), 256, 0, stream>>>(local, rqW + DD * i, rqb + DM * i, bufQ, nullptr,
                                               nullptr, ML, DM, DM);
    gemm_k<0><<<dim3(6, 256), 256, 0, stream>>>(scene, rkW + DD * i, rkb + DM * i, bufK, nullptr,
                                                nullptr, MS, DM, DM);
    gemm_k<0><<<dim3(6, 256), 256, 0, stream>>>(scene, rvW + DD * i, rvb + DM * i, bufV, nullptr,
                                                nullptr, MS, DM, DM);
    attn_k<<<dim3(BATCH * NHD * 2), 256, 0, stream>>>(bufQ, DM, bufK, DM, bufV, DM, bufO, lcos,
                                                      lsin, LBS, scos, ssin, 0, NLOC, NSC);
    gemm_k<2><<<dim3(6, 49), 256, 0, stream>>>(bufO, roW + DD * i, rob + DM * i, local, local,
                                               read_gate + DM * i, ML, DM, DM);
    // ---- backend block on local
    ln_k<<<ML / 4, 256, 0, stream>>>(local, ln1w + DM * i, ln1b + DM * i, bufH, ML);
    gemm_k<0><<<dim3(18, 49), 256, 0, stream>>>(bufH, Wqkv + (size_t)DM * 3 * DM * i,
                                                bqkv + 3 * DM * i, bufQ, nullptr, nullptr, ML,
                                                3 * DM, DM);
    attn_k<<<dim3(BATCH * NHD * 2), 256, 0, stream>>>(bufQ, 3 * DM, bufQ + DM, 3 * DM,
                                                      bufQ + 2 * DM, 3 * DM, bufO, lcos, lsin,
                                                      LBS, lcos, lsin, LBS, NLOC, NLOC);
    gemm_k<2><<<dim3(6, 49), 256, 0, stream>>>(bufO, Wp + DD * i, bp + DM * i, local, local,
                                               nullptr, ML, DM, DM);
    ln_k<<<ML / 4, 256, 0, stream>>>(local, ln2w + DM * i, ln2b + DM * i, bufH, ML);
    gemm_k<1><<<dim3(24, 49), 256, 0, stream>>>(bufH, W1 + (size_t)DM * 4 * DM * i,
                                                b1 + 4 * DM * i, bufO, nullptr, nullptr, ML,
                                                4 * DM, DM);
    gemm_k<2><<<dim3(6, 49), 256, 0, stream>>>(bufO, W2 + (size_t)DM * 4 * DM * i, b2 + DM * i,
                                               local, local, nullptr, ML, DM, 4 * DM);
    // ---- write cross-attn: scene(256q) <- local(49kv), gated residual into scene
    gemm_k<0><<<dim3(6, 256), 256, 0, stream>>>(scene, wqW + DD * i, wqb + DM * i, bufQ, nullptr,
                                                nullptr, MS, DM, DM);
    gemm_k<0><<<dim3(6, 49), 256, 0, stream>>>(local, wkW + DD * i, wkb + DM * i, bufK, nullptr,
                                               nullptr, ML, DM, DM);
    gemm_k<0><<<dim3(6, 49), 256, 0, stream>>>(local, wvW + DD * i, wvb + DM * i, bufV, nullptr,
                                               nullptr, ML, DM, DM);
    attn_k<<<dim3(BATCH * NHD * 8), 256, 0, stream>>>(bufQ, DM, bufK, DM, bufV, DM, bufO, scos,
                                                      ssin, 0, lcos, lsin, LBS, NSC, NLOC);
    gemm_k<2><<<dim3(6, 256), 256, 0, stream>>>(bufO, woW + DD * i, wob + DM * i, scene, scene,
                                                write_gate + DM * i, MS, DM, DM);
  }
}

// Round 2
// 7833.443 us; speedup vs baseline: 2.5804x; 2.5804x over previous
//
#include <hip/hip_runtime.h>
#include <hip/hip_bf16.h>
#include <math.h>

#define BATCH 64
#define DM 768
#define NHD 12
#define NLAYER 8
#define NLOC 49
#define NSC 256
#define ATT_SCALE 0.125f
#define QT 32
#define ML (BATCH * NLOC)      // 3136
#define ML_PAD 3200            // 25 * 128
#define MS (BATCH * NSC)       // 16384

typedef short bf16x8 __attribute__((ext_vector_type(8)));
typedef float f32x4 __attribute__((ext_vector_type(4)));

__device__ __forceinline__ float bf2f(unsigned short r) {
  return __uint_as_float(((unsigned)r) << 16);
}
__device__ __forceinline__ unsigned short f2bf(float x) {
  __hip_bfloat16 h = __float2bfloat16(x);
  unsigned short r;
  __builtin_memcpy(&r, &h, 2);
  return r;
}

// ------------------------------------------------------------------
// rope tables (fp32)
// ------------------------------------------------------------------
__global__ void rope_local_k(const float* __restrict__ centers, const float* __restrict__ scales,
                             const float* __restrict__ periods, float* __restrict__ lcos,
                             float* __restrict__ lsin) {
  int t = blockIdx.x * blockDim.x + threadIdx.x;
  const int total = BATCH * NLOC * 32;
  if (t >= total) return;
  int d = t & 31;
  int r = (t >> 5) % NLOC;
  int b = t / (NLOC * 32);
  int pi = d & 15;
  float gx = ((r % 7) + 0.5f) / 7.0f - 0.5f;
  float gy = ((r / 7) + 0.5f) / 7.0f - 0.5f;
  float coord = (d < 16) ? (centers[b * 2 + 0] + scales[b * 2 + 0] * gx)
                         : (centers[b * 2 + 1] + scales[b * 2 + 1] * gy);
  float ang = 6.283185307179586f * coord / periods[pi];
  lcos[t] = cosf(ang);
  lsin[t] = sinf(ang);
}

__global__ void rope_scene_k(const float* __restrict__ periods, float* __restrict__ scos,
                             float* __restrict__ ssin) {
  int t = blockIdx.x * blockDim.x + threadIdx.x;
  const int total = NSC * 32;
  if (t >= total) return;
  int d = t & 31;
  int r = t >> 5;
  int pi = d & 15;
  float coord = (d < 16) ? ((r % 16) + 0.5f) / 16.0f : ((r / 16) + 0.5f) / 16.0f;
  float ang = 6.283185307179586f * coord / periods[pi];
  scos[t] = cosf(ang);
  ssin[t] = sinf(ang);
}

// ------------------------------------------------------------------
// init: streams (fp32 in d_out) + bf16 mirrors
// ------------------------------------------------------------------
__global__ void init_out_k(const float* __restrict__ local_in, const float* __restrict__ scene_tok,
                           float* __restrict__ out, unsigned short* __restrict__ lbf,
                           unsigned short* __restrict__ sbf) {
  int t = blockIdx.x * blockDim.x + threadIdx.x;
  const int NL = ML * DM;
  const int NS = MS * DM;
  if (t < NL) {
    float v = local_in[t];
    out[t] = v;
    lbf[t] = f2bf(v);
  } else if (t < NL + NS) {
    float v = scene_tok[(t - NL) % (NSC * DM)];
    out[t] = v;
    sbf[t - NL] = f2bf(v);
  }
}

// ------------------------------------------------------------------
// per-layer weight convert + transpose: fp32 [K,N] -> bf16 [N,K]
// 12 matrices, fixed shapes across layers; 32x32 LDS tiles.
// ------------------------------------------------------------------
struct SrcPtrs {
  const float* p[12];
};

// order: qkv, wp, w1, w2, rq, rk, rv, ro, wq, wk, wv, wo
__constant__ const int wc_K[12] = {768, 768, 768, 3072, 768, 768, 768, 768, 768, 768, 768, 768};
__constant__ const int wc_N[12] = {2304, 768, 3072, 768, 768, 768, 768, 768, 768, 768, 768, 768};
__constant__ const int wc_blk[13] = {0,    1728, 2304, 4608, 6912,  7488,  8064,
                                     8640, 9216, 9792, 10368, 10944, 11520};
__constant__ const size_t wc_off[12] = {0,       1769472, 2359296, 4718592,
                                        7077888, 7667712, 8257536, 8847360,
                                        9437184, 10027008, 10616832, 11206656};
#define W_QKV 0
#define W_P 1769472
#define W_1 2359296
#define W_2 4718592
#define W_RQ 7077888
#define W_RK 7667712
#define W_RV 8257536
#define W_RO 8847360
#define W_WQ 9437184
#define W_WK 10027008
#define W_WV 10616832
#define W_WO 11206656

__global__ __launch_bounds__(256) void wconv_k(SrcPtrs sp, unsigned short* __restrict__ dst) {
  int b = blockIdx.x;
  int mi = 0;
  while (b >= wc_blk[mi + 1]) ++mi;
  int lb = b - wc_blk[mi];
  int K = wc_K[mi], N = wc_N[mi];
  int ncol = N >> 5;
  int kt = lb / ncol, nt = lb - kt * ncol;
  const float* src = sp.p[mi];
  __shared__ unsigned short tile[32][33];
  int r = threadIdx.x >> 3, c4 = (threadIdx.x & 7) << 2;
  float4 v = *(const float4*)(src + (size_t)(kt * 32 + r) * N + nt * 32 + c4);
  tile[r][c4 + 0] = f2bf(v.x);
  tile[r][c4 + 1] = f2bf(v.y);
  tile[r][c4 + 2] = f2bf(v.z);
  tile[r][c4 + 3] = f2bf(v.w);
  __syncthreads();
  unsigned short o[4];
  o[0] = tile[c4 + 0][r];
  o[1] = tile[c4 + 1][r];
  o[2] = tile[c4 + 2][r];
  o[3] = tile[c4 + 3][r];
  unsigned short* dp = dst + wc_off[mi] + (size_t)(nt * 32 + r) * K + kt * 32 + c4;
  *(ushort4*)dp = *(const ushort4*)o;
}

// ------------------------------------------------------------------
// bf16 MFMA GEMM: C[M,N] = A[M,K] @ Bt[N,K]^T + bias
// 128x128 tile, BK=64, 256 threads = 4 waves (2x2 of 64x64), 16x16x32 MFMA.
// global_load_lds(16B) staging with XOR chunk swizzle (8 chunks of 16B/row).
// MODE 0: store bf16 Cb. MODE 1: exact GELU, store bf16 Cb.
// MODE 2: Cf = Cf + gate*(acc+bias) (fp32 stream) + bf16 mirror Cb.
// ------------------------------------------------------------------
template <int MODE>
__global__ __launch_bounds__(256) void gemm_mfma(const unsigned short* __restrict__ A,
                                                 const unsigned short* __restrict__ Bt,
                                                 const float* __restrict__ bias,
                                                 unsigned short* __restrict__ Cb,
                                                 float* __restrict__ Cf,
                                                 const float* __restrict__ gate, int M, int N,
                                                 int K) {
  __shared__ unsigned short As[128 * 64];
  __shared__ unsigned short Bs[128 * 64];
  const int tid = threadIdx.x;
  const int w = tid >> 6;
  const int lane = tid & 63;
  const int wm = w & 1, wn = w >> 1;
  const int bm = blockIdx.y << 7;
  const int bn = blockIdx.x << 7;
  const int lrow = lane >> 3;    // 0..7
  const int lchunk = lane & 7;   // dest chunk
  const int schunk = lchunk ^ lrow;  // swizzled source chunk
  const int fm = lane & 15;
  const int quad = lane >> 4;

  f32x4 acc[4][4];
#pragma unroll
  for (int i = 0; i < 4; ++i)
#pragma unroll
    for (int j = 0; j < 4; ++j) acc[i][j] = (f32x4){0.f, 0.f, 0.f, 0.f};

  const size_t a_base = (size_t)(bm + w * 32 + lrow) * K + schunk * 8;
  const size_t b_base = (size_t)(bn + w * 32 + lrow) * K + schunk * 8;

  for (int k0 = 0; k0 < K; k0 += 64) {
    __syncthreads();
#pragma unroll
    for (int q = 0; q < 4; ++q) {
      const unsigned short* ga = A + a_base + (size_t)(q * 8) * K + k0;
      const unsigned short* gb = Bt + b_base + (size_t)(q * 8) * K + k0;
      __builtin_amdgcn_global_load_lds((const __attribute__((address_space(1))) void*)ga,
                                       (__attribute__((address_space(3))) void*)(As + (w * 32 + q * 8) * 64),
                                       16, 0, 0);
      __builtin_amdgcn_global_load_lds((const __attribute__((address_space(1))) void*)gb,
                                       (__attribute__((address_space(3))) void*)(Bs + (w * 32 + q * 8) * 64),
                                       16, 0, 0);
    }
    __syncthreads();
#pragma unroll
    for (int kc = 0; kc < 2; ++kc) {
      bf16x8 af[4], bfr[4];
#pragma unroll
      for (int i = 0; i < 4; ++i) {
        int ra = wm * 64 + i * 16 + fm;
        af[i] = *(const bf16x8*)(As + ra * 64 + (((kc * 4 + quad) ^ (ra & 7)) << 3));
      }
#pragma unroll
      for (int j = 0; j < 4; ++j) {
        int rb = wn * 64 + j * 16 + fm;
        bfr[j] = *(const bf16x8*)(Bs + rb * 64 + (((kc * 4 + quad) ^ (rb & 7)) << 3));
      }
#pragma unroll
      for (int i = 0; i < 4; ++i)
#pragma unroll
        for (int j = 0; j < 4; ++j)
          acc[i][j] = __builtin_amdgcn_mfma_f32_16x16x32_bf16(af[i], bfr[j], acc[i][j], 0, 0, 0);
    }
  }

  // epilogue: lane holds D[quad*4+reg][fm] of each 16x16 tile
#pragma unroll
  for (int j = 0; j < 4; ++j) {
    const int col = bn + wn * 64 + j * 16 + fm;
    const float bj = bias[col];
    float gj = 1.0f;
    if (MODE == 2) gj = gate ? gate[col] : 1.0f;
#pragma unroll
    for (int i = 0; i < 4; ++i) {
#pragma unroll
      for (int reg = 0; reg < 4; ++reg) {
        const int row = bm + wm * 64 + i * 16 + quad * 4 + reg;
        if (row < M) {
          float v = acc[i][j][reg] + bj;
          if (MODE == 1) v = 0.5f * v * (1.0f + erff(v * 0.7071067811865475f));
          const size_t idx = (size_t)row * N + col;
          if (MODE == 2) {
            float o = Cf[idx] + gj * v;
            Cf[idx] = o;
            Cb[idx] = f2bf(o);
          } else {
            Cb[idx] = f2bf(v);
          }
        }
      }
    }
  }
}

// ------------------------------------------------------------------
// LayerNorm over D=768; fp32 in, bf16 out; one wave per row
// ------------------------------------------------------------------
__global__ __launch_bounds__(256) void ln_k(const float* __restrict__ X,
                                            const float* __restrict__ w,
                                            const float* __restrict__ bb,
                                            unsigned short* __restrict__ Y, int rows) {
  const int wid = threadIdx.x >> 6, lane = threadIdx.x & 63;
  const int row = blockIdx.x * 4 + wid;
  if (row >= rows) return;
  const float* x = X + (size_t)row * DM;
  float v[12];
  float s = 0.f;
#pragma unroll
  for (int j = 0; j < 12; ++j) {
    v[j] = x[lane + 64 * j];
    s += v[j];
  }
#pragma unroll
  for (int o = 32; o; o >>= 1) s += __shfl_xor(s, o, 64);
  float mean = s * (1.0f / 768.0f);
  float q = 0.f;
#pragma unroll
  for (int j = 0; j < 12; ++j) {
    float d0 = v[j] - mean;
    q += d0 * d0;
  }
#pragma unroll
  for (int o = 32; o; o >>= 1) q += __shfl_xor(q, o, 64);
  float inv = rsqrtf(q * (1.0f / 768.0f) + 1e-6f);
#pragma unroll
  for (int j = 0; j < 12; ++j) {
    int d0 = lane + 64 * j;
    Y[(size_t)row * DM + d0] = f2bf((v[j] - mean) * inv * w[d0] + bb[d0]);
  }
}

// ------------------------------------------------------------------
// Fused attention (fp32 compute, bf16 in/out); one (b,h,q-tile-32) per block
// ------------------------------------------------------------------
__global__ __launch_bounds__(256) void attn_k(const unsigned short* __restrict__ Q, int qs,
                                              const unsigned short* __restrict__ K, int ks,
                                              const unsigned short* __restrict__ V, int vs,
                                              unsigned short* __restrict__ O,
                                              const float* __restrict__ qcos,
                                              const float* __restrict__ qsin, int qbs,
                                              const float* __restrict__ kcos,
                                              const float* __restrict__ ksin, int kbs, int Nq,
                                              int Nk) {
  __shared__ float q_s[QT][64];
  __shared__ float k_sT[64][68];
  __shared__ float sc[QT][NSC];
  const int tid = threadIdx.x;
  const int nQT = (Nq + QT - 1) / QT;
  const int qt = blockIdx.x % nQT;
  const int h = (blockIdx.x / nQT) % NHD;
  const int b = blockIdx.x / (nQT * NHD);
  const int n0 = qt * QT;
  const int nrows = (Nq - n0 < QT) ? (Nq - n0) : QT;

  for (int idx = tid; idx < nrows * 64; idx += 256) {
    int r = idx >> 6, d = idx & 63, dd = d & 31;
    int n = n0 + r;
    size_t base = ((size_t)b * Nq + n) * qs + h * 64;
    float c = qcos[(size_t)b * qbs + n * 32 + dd];
    float s = qsin[(size_t)b * qbs + n * 32 + dd];
    float x1 = bf2f(Q[base + dd]), x2 = bf2f(Q[base + dd + 32]);
    q_s[r][d] = (d < 32) ? (x1 * c - x2 * s) : (x1 * s + x2 * c);
  }

  const int rt = tid >> 4, mt = tid & 15;
  const int r0 = rt * 2;
  for (int m0 = 0; m0 < Nk; m0 += 64) {
    int mc = (Nk - m0 < 64) ? (Nk - m0) : 64;
    __syncthreads();
    for (int idx = tid; idx < mc * 64; idx += 256) {
      int r = idx >> 6, d = idx & 63, dd = d & 31;
      int m = m0 + r;
      size_t base = ((size_t)b * Nk + m) * ks + h * 64;
      float c = kcos[(size_t)b * kbs + m * 32 + dd];
      float s = ksin[(size_t)b * kbs + m * 32 + dd];
      float x1 = bf2f(K[base + dd]), x2 = bf2f(K[base + dd + 32]);
      k_sT[d][r] = (d < 32) ? (x1 * c - x2 * s) : (x1 * s + x2 * c);
    }
    __syncthreads();
    float a0[4] = {0, 0, 0, 0}, a1[4] = {0, 0, 0, 0};
#pragma unroll 8
    for (int d = 0; d < 64; ++d) {
      float4 kv = *(const float4*)&k_sT[d][mt << 2];
      float q0 = q_s[r0][d];
      float q1 = q_s[r0 + 1][d];
      a0[0] = fmaf(q0, kv.x, a0[0]);
      a0[1] = fmaf(q0, kv.y, a0[1]);
      a0[2] = fmaf(q0, kv.z, a0[2]);
      a0[3] = fmaf(q0, kv.w, a0[3]);
      a1[0] = fmaf(q1, kv.x, a1[0]);
      a1[1] = fmaf(q1, kv.y, a1[1]);
      a1[2] = fmaf(q1, kv.z, a1[2]);
      a1[3] = fmaf(q1, kv.w, a1[3]);
    }
    const int mloc = mt << 2;
    if (r0 < nrows) {
#pragma unroll
      for (int j = 0; j < 4; ++j)
        if (mloc + j < mc) sc[r0][m0 + mloc + j] = a0[j] * ATT_SCALE;
    }
    if (r0 + 1 < nrows) {
#pragma unroll
      for (int j = 0; j < 4; ++j)
        if (mloc + j < mc) sc[r0 + 1][m0 + mloc + j] = a1[j] * ATT_SCALE;
    }
  }
  __syncthreads();

  const int wid = tid >> 6, lane = tid & 63;
  for (int r = wid; r < nrows; r += 4) {
    float mx = -1e30f;
    for (int m = lane; m < Nk; m += 64) mx = fmaxf(mx, sc[r][m]);
#pragma unroll
    for (int o = 32; o; o >>= 1) mx = fmaxf(mx, __shfl_xor(mx, o, 64));
    float sum = 0.f;
    for (int m = lane; m < Nk; m += 64) {
      float e = __expf(sc[r][m] - mx);
      sc[r][m] = e;
      sum += e;
    }
#pragma unroll
    for (int o = 32; o; o >>= 1) sum += __shfl_xor(sum, o, 64);
    float inv = 1.0f / sum;
    for (int m = lane; m < Nk; m += 64) sc[r][m] *= inv;
  }
  __syncthreads();

  float acc[8] = {0, 0, 0, 0, 0, 0, 0, 0};
  for (int m = 0; m < Nk; ++m) {
    float v = bf2f(V[((size_t)b * Nk + m) * vs + h * 64 + lane]);
#pragma unroll
    for (int rr = 0; rr < 8; ++rr) acc[rr] = fmaf(sc[wid + (rr << 2)][m], v, acc[rr]);
  }
#pragma unroll
  for (int rr = 0; rr < 8; ++rr) {
    int r = wid + (rr << 2);
    if (r < nrows) O[((size_t)b * Nq + n0 + r) * DM + h * 64 + lane] = f2bf(acc[rr]);
  }
}

// ------------------------------------------------------------------
extern "C" void kernel_launch(void* const* d_in, const int* in_sizes, int n_in, void* d_out,
                              int out_size, void* d_ws, size_t ws_size, hipStream_t stream) {
  const float* local_in = (const float*)d_in[0];
  const float* centers = (const float*)d_in[1];
  const float* scales = (const float*)d_in[2];
  const float* scene_tok = (const float*)d_in[3];
  const float* periods = (const float*)d_in[4];
  const float* read_gate = (const float*)d_in[5];
  const float* write_gate = (const float*)d_in[6];
  const float* ln1w = (const float*)d_in[7];
  const float* ln1b = (const float*)d_in[8];
  const float* ln2w = (const float*)d_in[9];
  const float* ln2b = (const float*)d_in[10];
  const float* Wqkv = (const float*)d_in[11];
  const float* bqkv = (const float*)d_in[12];
  const float* Wp = (const float*)d_in[13];
  const float* bp = (const float*)d_in[14];
  const float* W1 = (const float*)d_in[15];
  const float* b1 = (const float*)d_in[16];
  const float* W2 = (const float*)d_in[17];
  const float* b2 = (const float*)d_in[18];
  const float* rqW = (const float*)d_in[19];
  const float* rqb = (const float*)d_in[20];
  const float* rkW = (const float*)d_in[21];
  const float* rkb = (const float*)d_in[22];
  const float* rvW = (const float*)d_in[23];
  const float* rvb = (const float*)d_in[24];
  const float* roW = (const float*)d_in[25];
  const float* rob = (const float*)d_in[26];
  const float* wqW = (const float*)d_in[27];
  const float* wqb = (const float*)d_in[28];
  const float* wkW = (const float*)d_in[29];
  const float* wkb = (const float*)d_in[30];
  const float* wvW = (const float*)d_in[31];
  const float* wvb = (const float*)d_in[32];
  const float* woW = (const float*)d_in[33];
  const float* wob = (const float*)d_in[34];

  float* out = (float*)d_out;
  float* local = out;                              // (3136, 768) fp32
  float* scene = out + (size_t)ML * DM;            // (16384, 768) fp32

  // workspace layout (bf16 = unsigned short)
  constexpr size_t E_WSLOT = 11796480;             // per-layer weights bf16 [N][K]
  constexpr size_t E_LBF = (size_t)ML_PAD * DM;    // 2457600
  constexpr size_t E_BUF = (size_t)MS * DM;        // 12582912
  unsigned short* wslot = (unsigned short*)d_ws;
  unsigned short* local_bf = wslot + E_WSLOT;
  unsigned short* scene_bf = local_bf + E_LBF;
  unsigned short* bufQ = scene_bf + E_BUF;
  unsigned short* bufK = bufQ + E_BUF;
  unsigned short* bufV = bufK + E_BUF;
  unsigned short* bufO = bufV + E_BUF;
  unsigned short* bufH = bufO + E_BUF;
  float* lcos = (float*)(bufH + E_LBF);
  float* lsin = lcos + BATCH * NLOC * 32;
  float* scos = lsin + BATCH * NLOC * 32;
  float* ssin = scos + NSC * 32;

  const int totOut = (ML + MS) * DM;
  init_out_k<<<(totOut + 255) / 256, 256, 0, stream>>>(local_in, scene_tok, out, local_bf,
                                                       scene_bf);
  rope_local_k<<<(BATCH * NLOC * 32 + 255) / 256, 256, 0, stream>>>(centers, scales, periods,
                                                                    lcos, lsin);
  rope_scene_k<<<(NSC * 32 + 255) / 256, 256, 0, stream>>>(periods, scos, ssin);

  const size_t DD = (size_t)DM * DM;
  const int LBS = NLOC * 32;
  const dim3 gS(6, MS / 128);    // scene-M 768-N
  const dim3 gL(6, ML_PAD / 128);  // local-M 768-N
  for (int i = 0; i < NLAYER; ++i) {
    SrcPtrs sp;
    sp.p[0] = Wqkv + (size_t)DM * 3 * DM * i;
    sp.p[1] = Wp + DD * i;
    sp.p[2] = W1 + (size_t)DM * 4 * DM * i;
    sp.p[3] = W2 + (size_t)4 * DM * DM * i;
    sp.p[4] = rqW + DD * i;
    sp.p[5] = rkW + DD * i;
    sp.p[6] = rvW + DD * i;
    sp.p[7] = roW + DD * i;
    sp.p[8] = wqW + DD * i;
    sp.p[9] = wkW + DD * i;
    sp.p[10] = wvW + DD * i;
    sp.p[11] = woW + DD * i;
    wconv_k<<<11520, 256, 0, stream>>>(sp, wslot);

    // ---- read cross-attn: local(49q) <- scene(256kv)
    gemm_mfma<0><<<gL, 256, 0, stream>>>(local_bf, wslot + W_RQ, rqb + DM * i, bufQ, nullptr,
                                         nullptr, ML, DM, DM);
    gemm_mfma<0><<<gS, 256, 0, stream>>>(scene_bf, wslot + W_RK, rkb + DM * i, bufK, nullptr,
                                         nullptr, MS, DM, DM);
    gemm_mfma<0><<<gS, 256, 0, stream>>>(scene_bf, wslot + W_RV, rvb + DM * i, bufV, nullptr,
                                         nullptr, MS, DM, DM);
    attn_k<<<dim3(BATCH * NHD * 2), 256, 0, stream>>>(bufQ, DM, bufK, DM, bufV, DM, bufO, lcos,
                                                      lsin, LBS, scos, ssin, 0, NLOC, NSC);
    gemm_mfma<2><<<gL, 256, 0, stream>>>(bufO, wslot + W_RO, rob + DM * i, local_bf, local,
                                         read_gate + DM * i, ML, DM, DM);
    // ---- backend block on local
    ln_k<<<ML / 4, 256, 0, stream>>>(local, ln1w + DM * i, ln1b + DM * i, bufH, ML);
    gemm_mfma<0><<<dim3(18, ML_PAD / 128), 256, 0, stream>>>(bufH, wslot + W_QKV,
                                                             bqkv + 3 * DM * i, bufQ, nullptr,
                                                             nullptr, ML, 3 * DM, DM);
    attn_k<<<dim3(BATCH * NHD * 2), 256, 0, stream>>>(bufQ, 3 * DM, bufQ + DM, 3 * DM,
                                                      bufQ + 2 * DM, 3 * DM, bufO, lcos, lsin,
                                                      LBS, lcos, lsin, LBS, NLOC, NLOC);
    gemm_mfma<2><<<gL, 256, 0, stream>>>(bufO, wslot + W_P, bp + DM * i, local_bf, local, nullptr,
                                         ML, DM, DM);
    ln_k<<<ML / 4, 256, 0, stream>>>(local, ln2w + DM * i, ln2b + DM * i, bufH, ML);
    gemm_mfma<1><<<dim3(24, ML_PAD / 128), 256, 0, stream>>>(bufH, wslot + W_1, b1 + 4 * DM * i,
                                                             bufO, nullptr, nullptr, ML, 4 * DM,
                                                             DM);
    gemm_mfma<2><<<gL, 256, 0, stream>>>(bufO, wslot + W_2, b2 + DM * i, local_bf, local, nullptr,
                                         ML, DM, 4 * DM);
    // ---- write cross-attn: scene(256q) <- local(49kv)
    gemm_mfma<0><<<gS, 256, 0, stream>>>(scene_bf, wslot + W_WQ, wqb + DM * i, bufQ, nullptr,
                                         nullptr, MS, DM, DM);
    gemm_mfma<0><<<gL, 256, 0, stream>>>(local_bf, wslot + W_WK, wkb + DM * i, bufK, nullptr,
                                         nullptr, ML, DM, DM);
    gemm_mfma<0><<<gL, 256, 0, stream>>>(local_bf, wslot + W_WV, wvb + DM * i, bufV, nullptr,
                                         nullptr, ML, DM, DM);
    attn_k<<<dim3(BATCH * NHD * 8), 256, 0, stream>>>(bufQ, DM, bufK, DM, bufV, DM, bufO, scos,
                                                      ssin, 0, lcos, lsin, LBS, NSC, NLOC);
    gemm_mfma<2><<<gS, 256, 0, stream>>>(bufO, wslot + W_WO, wob + DM * i, scene_bf, scene,
                                         write_gate + DM * i, MS, DM, DM);
  }
}